// Round 4
// baseline (2110.007 us; speedup 1.0000x reference)
//
#include <hip/hip_runtime.h>
#include <hip/hip_bf16.h>
#include <stdint.h>

#define NB 16
#define NPTS 4096
#define NS 1024
#define NK 32
#define NT_COLS (NB*NS*NK)   // 524288 columns (b*NS+s)*NK + k

typedef __hip_bfloat16 bf16;

__global__ void k_zero(float* __restrict__ p) { p[threadIdx.x] = 0.f; }

// ---------------- FPS: one block per batch, exact fp32 replication ----------
// Inputs fp32 (B,3,N); output0 fp32 (B,3,NS) = exact copies of selected coords.
// Index selection replicates np bit-exactly (no FMA, sequential 3-term sums,
// first-occurrence argmax).
__global__ __launch_bounds__(512) void k_fps(const float* __restrict__ xyz,
                                             float* __restrict__ newxyz,
                                             float* __restrict__ out0) {
  __shared__ float xs[NPTS], ys[NPTS], zs[NPTS];
  __shared__ float redv[8];
  __shared__ int   redi[8];
  __shared__ int   s_cur;
  const int b = blockIdx.x;
  const int t = threadIdx.x;
  const float* p = xyz + (size_t)b * 3 * NPTS;
  for (int i = t; i < NPTS; i += 512) {
    xs[i] = p[i];
    ys[i] = p[NPTS + i];
    zs[i] = p[2*NPTS + i];
  }
  __syncthreads();
  float px[8], py[8], pz[8], dist[8];
  const int p0 = t * 8;
  #pragma unroll
  for (int j = 0; j < 8; ++j) { px[j]=xs[p0+j]; py[j]=ys[p0+j]; pz[j]=zs[p0+j]; dist[j]=1e10f; }
  const int lane = t & 63, wv = t >> 6;
  int cur = 0;
  for (int i = 0; i < NS; ++i) {
    if (t == 0) {
      float cx = xs[cur], cy = ys[cur], cz = zs[cur];
      size_t o = (size_t)(b*NS + i)*3;
      newxyz[o] = cx; newxyz[o+1] = cy; newxyz[o+2] = cz;
      size_t q = (size_t)b*3*NS + i;
      out0[q]        = cx;        // fp32 out: bit-exact copy
      out0[q + NS]   = cy;
      out0[q + 2*NS] = cz;
    }
    if (i == NS-1) break;
    float cx = xs[cur], cy = ys[cur], cz = zs[cur];
    float bv = -1.0f; int bi = 0;
    #pragma unroll
    for (int j = 0; j < 8; ++j) {
      // exact replication of np: (x-c)**2 elementwise, sequential sum, no FMA
      float dx = __fsub_rn(px[j], cx);
      float dy = __fsub_rn(py[j], cy);
      float dz = __fsub_rn(pz[j], cz);
      float d  = __fadd_rn(__fadd_rn(__fmul_rn(dx,dx), __fmul_rn(dy,dy)), __fmul_rn(dz,dz));
      float nd = fminf(dist[j], d);
      dist[j] = nd;
      if (nd > bv) { bv = nd; bi = p0 + j; }   // strict > => first occurrence
    }
    #pragma unroll
    for (int off = 32; off; off >>= 1) {
      float ov = __shfl_xor(bv, off);
      int   oi = __shfl_xor(bi, off);
      if (ov > bv || (ov == bv && oi < bi)) { bv = ov; bi = oi; }
    }
    if (lane == 0) { redv[wv] = bv; redi[wv] = bi; }
    __syncthreads();
    if (t == 0) {
      float best = redv[0]; int besti = redi[0];
      #pragma unroll
      for (int w8 = 1; w8 < 8; ++w8) {
        if (redv[w8] > best || (redv[w8] == best && redi[w8] < besti)) { best = redv[w8]; besti = redi[w8]; }
      }
      s_cur = besti;
    }
    __syncthreads();
    cur = s_cur;
  }
}

// ---------------- Ball query: one wave per query ----------------------------
__global__ __launch_bounds__(256) void k_ballq(const float* __restrict__ xyz,
                                               const float* __restrict__ newxyz,
                                               int* __restrict__ idx) {
  const int gw = (blockIdx.x * 256 + threadIdx.x) >> 6;   // global wave = query
  const int lane = threadIdx.x & 63;
  const int b = gw >> 10;
  const int s = gw & (NS-1);
  const float* xb = xyz + (size_t)b * 3 * NPTS;
  const size_t nq = (size_t)(b*NS + s)*3;
  const float nx = newxyz[nq], ny = newxyz[nq+1], nz = newxyz[nq+2];
  const float sn = __fadd_rn(__fadd_rn(__fmul_rn(nx,nx), __fmul_rn(ny,ny)), __fmul_rn(nz,nz));
  const float R2 = (float)(0.2*0.2);   // f32 0.04; same keep-set as np's f64 compare
  int* out = idx + (size_t)gw * NK;
  int cnt = 0, first = 0;
  for (int c0 = 0; c0 < NPTS; c0 += 64) {
    int n = c0 + lane;
    float x = xb[n], y = xb[NPTS+n], z = xb[2*NPTS+n];
    float sx = __fadd_rn(__fadd_rn(__fmul_rn(x,x), __fmul_rn(y,y)), __fmul_rn(z,z));
    float dt = __fadd_rn(__fadd_rn(__fmul_rn(nx,x), __fmul_rn(ny,y)), __fmul_rn(nz,z));
    float sqr = __fsub_rn(__fadd_rn(sn, sx), __fmul_rn(2.0f, dt));
    bool inr = (sqr <= R2);                 // kept iff NOT (sqr > r^2)
    unsigned long long m = __ballot(inr);
    if (m != 0ull) {
      if (cnt == 0) first = c0 + (int)__builtin_ctzll(m);
      int rank = __popcll(m & ((1ull << lane) - 1ull));
      int pos = cnt + rank;
      if (inr && pos < NK) out[pos] = n;
      cnt += __popcll(m);
      if (cnt >= NK) break;
    }
  }
  int tot = cnt < NK ? cnt : NK;
  if (lane >= tot && lane < NK) out[lane] = first;
}

// ---------------- Layer 1: gather + 6->64 conv -----------------------------
__global__ __launch_bounds__(256) void k_layer1(const float* __restrict__ xyz,
                                                const float* __restrict__ feat,
                                                const float* __restrict__ newxyz,
                                                const int* __restrict__ idx,
                                                const float* __restrict__ w0,
                                                const float* __restrict__ b0,
                                                bf16* __restrict__ x1) {
  __shared__ float w[64*6];
  __shared__ float bias[64];
  for (int i = threadIdx.x; i < 64*6; i += 256) w[i] = w0[i];
  if (threadIdx.x < 64) bias[threadIdx.x] = b0[threadIdx.x];
  __syncthreads();
  const int col = blockIdx.x * 256 + threadIdx.x;   // (b*NS+s)*NK + k
  const int bs = col >> 5;                          // b*NS + s
  const int b  = bs >> 10;
  const int n  = idx[col];
  const float* xb = xyz  + (size_t)b*3*NPTS;
  const float* fb = feat + (size_t)b*3*NPTS;
  float in[6];
  in[0] = __fsub_rn(xb[n],        newxyz[(size_t)bs*3]);
  in[1] = __fsub_rn(xb[NPTS+n],   newxyz[(size_t)bs*3+1]);
  in[2] = __fsub_rn(xb[2*NPTS+n], newxyz[(size_t)bs*3+2]);
  in[3] = fb[n];
  in[4] = fb[NPTS+n];
  in[5] = fb[2*NPTS+n];
  #pragma unroll
  for (int o = 0; o < 64; ++o) {
    float acc = bias[o];
    #pragma unroll
    for (int c = 0; c < 6; ++c) acc = fmaf(in[c], w[o*6+c], acc);
    x1[(size_t)o*NT_COLS + col] = __float2bfloat16(acc);
  }
}

// ---------------- Per-channel sum / sumsq (bf16 intermediates) --------------
__global__ __launch_bounds__(256) void k_stats(const bf16* __restrict__ x,
                                               float* __restrict__ accum, int C) {
  const int o = blockIdx.x >> 5;
  const int chunk = blockIdx.x & 31;
  const uint4* p = (const uint4*)(x + (size_t)o*NT_COLS + (size_t)chunk*16384);
  float s = 0.f, ss = 0.f;
  #pragma unroll
  for (int it = 0; it < 8; ++it) {
    uint4 u = p[threadIdx.x + it*256];
    uint32_t wr[4] = {u.x, u.y, u.z, u.w};
    #pragma unroll
    for (int q = 0; q < 4; ++q) {
      float a  = __uint_as_float(wr[q] << 16);
      float bq = __uint_as_float(wr[q] & 0xffff0000u);
      s += a;  ss = fmaf(a, a, ss);
      s += bq; ss = fmaf(bq, bq, ss);
    }
  }
  #pragma unroll
  for (int off = 32; off; off >>= 1) { s += __shfl_xor(s, off); ss += __shfl_xor(ss, off); }
  __shared__ float ls[4], lss[4];
  const int lane = threadIdx.x & 63, wv = threadIdx.x >> 6;
  if (lane == 0) { ls[wv] = s; lss[wv] = ss; }
  __syncthreads();
  if (threadIdx.x == 0) {
    atomicAdd(&accum[o],     (ls[0]+ls[1])+(ls[2]+ls[3]));
    atomicAdd(&accum[C + o], (lss[0]+lss[1])+(lss[2]+lss[3]));
  }
}

__global__ void k_finalize(const float* __restrict__ accum,
                           const float* __restrict__ g, const float* __restrict__ beta,
                           float* __restrict__ scsh, int C) {
  int o = blockIdx.x*256 + threadIdx.x;
  if (o < C) {
    const float n = (float)NT_COLS;
    float mu  = accum[o] / n;
    float var = accum[C+o] / n - mu*mu;
    if (var < 0.f) var = 0.f;
    float rs = rsqrtf(var + 1e-5f);
    float sc = g[o] * rs;
    scsh[o]   = sc;
    scsh[C+o] = beta[o] - mu * sc;
  }
}

// ---------------- Layers 2/3: BN+ReLU(in) then 64->CO GEMM -----------------
template<int CO>
__global__ __launch_bounds__(256) void k_layerN(const bf16* __restrict__ xin,
                                                const float* __restrict__ wN,
                                                const float* __restrict__ bN,
                                                const float* __restrict__ scsh,
                                                bf16* __restrict__ xout) {
  __shared__ float w[CO*64];
  __shared__ float bias[CO];
  __shared__ float sc[64], sh[64];
  for (int i = threadIdx.x; i < CO*64; i += 256) w[i] = wN[i];
  if (threadIdx.x < CO) bias[threadIdx.x] = bN[threadIdx.x];
  if (threadIdx.x < 64) { sc[threadIdx.x] = scsh[threadIdx.x]; sh[threadIdx.x] = scsh[64+threadIdx.x]; }
  __syncthreads();
  const int col = blockIdx.x * 256 + threadIdx.x;
  float y[64];
  #pragma unroll
  for (int c = 0; c < 64; ++c) {
    float v = __bfloat162float(xin[(size_t)c*NT_COLS + col]);
    v = fmaf(v, sc[c], sh[c]);
    y[c] = fmaxf(v, 0.f);
  }
  for (int o = 0; o < CO; ++o) {
    float acc = bias[o];
    #pragma unroll
    for (int c = 0; c < 64; ++c) acc = fmaf(w[o*64+c], y[c], acc);
    xout[(size_t)o*NT_COLS + col] = __float2bfloat16(acc);
  }
}

// ---------------- Max-pool over K with final BN+ReLU (fp32 out) -------------
__global__ __launch_bounds__(256) void k_maxpool(const bf16* __restrict__ x3,
                                                 const float* __restrict__ scsh,
                                                 float* __restrict__ out1) {
  const int t = blockIdx.x * 256 + threadIdx.x;  // (b*128+o)*NS + s
  const int s  = t & (NS-1);
  const int bo = t >> 10;
  const int o  = bo & 127;
  const int b  = bo >> 7;
  const float sc = scsh[o], sh = scsh[128+o];
  const uint4* p = (const uint4*)(x3 + (size_t)o*NT_COLS + (size_t)(b*NS + s)*NK);
  float m = 0.f;   // ReLU outputs are >= 0
  #pragma unroll
  for (int it = 0; it < 4; ++it) {
    uint4 u = p[it];
    uint32_t wr[4] = {u.x, u.y, u.z, u.w};
    #pragma unroll
    for (int q = 0; q < 4; ++q) {
      float a  = __uint_as_float(wr[q] << 16);
      float bq = __uint_as_float(wr[q] & 0xffff0000u);
      a  = fmaxf(fmaf(a,  sc, sh), 0.f);
      bq = fmaxf(fmaf(bq, sc, sh), 0.f);
      m = fmaxf(m, fmaxf(a, bq));
    }
  }
  out1[t] = m;
}

extern "C" void kernel_launch(void* const* d_in, const int* in_sizes, int n_in,
                              void* d_out, int out_size, void* d_ws, size_t ws_size,
                              hipStream_t stream) {
  const float* xyz  = (const float*)d_in[0];
  const float* feat = (const float*)d_in[1];
  const float* w0 = (const float*)d_in[2];
  const float* b0 = (const float*)d_in[3];
  const float* g0 = (const float*)d_in[4];
  const float* bt0= (const float*)d_in[5];
  const float* w1 = (const float*)d_in[6];
  const float* b1 = (const float*)d_in[7];
  const float* g1 = (const float*)d_in[8];
  const float* bt1= (const float*)d_in[9];
  const float* w2 = (const float*)d_in[10];
  const float* b2 = (const float*)d_in[11];
  const float* g2 = (const float*)d_in[12];
  const float* bt2= (const float*)d_in[13];

  float* out0 = (float*)d_out;                     // (B,3,NS) fp32
  float* out1 = out0 + (size_t)NB*3*NS;            // (B,128,NS) fp32

  // Workspace layout (total 203,628,544 B ~= 194 MB):
  //   accum@0, scsh@4096, newxyz@8192(fp32), bidx@204800,
  //   x2@2301952 (64MB), x1@69410816 (64MB), x3@69410816 (128MB, aliases dead x1)
  char* ws = (char*)d_ws;
  float* accum  = (float*)(ws + 0);
  float* scsh   = (float*)(ws + 4096);
  float* newxyz = (float*)(ws + 8192);
  int*   bidx   = (int*)  (ws + 204800);
  bf16*  x2     = (bf16*) (ws + 2301952);
  bf16*  x1     = (bf16*) (ws + 69410816);
  bf16*  x3     = (bf16*) (ws + 69410816);

  k_zero <<<1, 512, 0, stream>>>(accum);

  k_fps  <<<NB,   512, 0, stream>>>(xyz, newxyz, out0);
  k_ballq<<<16384/4, 256, 0, stream>>>(xyz, newxyz, bidx);
  k_layer1<<<NT_COLS/256, 256, 0, stream>>>(xyz, feat, newxyz, bidx, w0, b0, x1);

  k_stats   <<<64*32, 256, 0, stream>>>(x1, accum + 0, 64);
  k_finalize<<<1,     256, 0, stream>>>(accum + 0, g0, bt0, scsh + 0, 64);
  k_layerN<64><<<NT_COLS/256, 256, 0, stream>>>(x1, w1, b1, scsh + 0, x2);

  k_stats   <<<64*32, 256, 0, stream>>>(x2, accum + 128, 64);
  k_finalize<<<1,     256, 0, stream>>>(accum + 128, g1, bt1, scsh + 128, 64);
  k_layerN<128><<<NT_COLS/256, 256, 0, stream>>>(x2, w2, b2, scsh + 128, x3);

  k_stats   <<<128*32, 256, 0, stream>>>(x3, accum + 256, 128);
  k_finalize<<<1,      256, 0, stream>>>(accum + 256, g2, bt2, scsh + 256, 128);
  k_maxpool <<<(NB*128*NS)/256, 256, 0, stream>>>(x3, scsh + 256, out1);
}

// Round 5
// 1132.558 us; speedup vs baseline: 1.8630x; 1.8630x over previous
//
#include <hip/hip_runtime.h>
#include <hip/hip_bf16.h>
#include <stdint.h>

#define NB 16
#define NPTS 4096
#define NS 1024
#define NK 32
#define NT_COLS (NB*NS*NK)   // 524288 columns (b*NS+s)*NK + k

typedef __hip_bfloat16 bf16;

__global__ void k_zero(float* __restrict__ p) { p[threadIdx.x] = 0.f; }

// DPP-shifted fmax: returns fmax(x, dpp_mov(x)). Disabled/OOB lanes keep old=x
// (identity). CTRL/RM/BM are compile-time per builtin requirements.
template<int CTRL, int RM, int BM>
__device__ __forceinline__ float fmax_dpp(float x) {
  int o = __builtin_amdgcn_update_dpp(__float_as_int(x), __float_as_int(x),
                                      CTRL, RM, BM, false);
  return fmaxf(x, __int_as_float(o));
}

// ---------------- FPS: one block/batch, 256 thr, DPP argmax ----------------
// Exact np replication: per-point (x-c)^2 elementwise + sequential 3-term sum
// (no FMA); argmax tie-break = first occurrence (lane order == point order).
__global__ __launch_bounds__(256) void k_fps(const float* __restrict__ xyz,
                                             float* __restrict__ newxyz,
                                             float* __restrict__ out0) {
  __shared__ float xs[NPTS], ys[NPTS], zs[NPTS];
  __shared__ float2 pair[2][4];   // double-buffered (value, idx-bits) per wave
  const int b = blockIdx.x;
  const int t = threadIdx.x;
  const float* p = xyz + (size_t)b * 3 * NPTS;
  for (int i = t; i < NPTS; i += 256) {
    xs[i] = p[i];
    ys[i] = p[NPTS + i];
    zs[i] = p[2*NPTS + i];
  }
  __syncthreads();
  float px[16], py[16], pz[16], dist[16];
  const int p0 = t * 16;          // wave w owns points [w*1024, w*1024+1024)
  #pragma unroll
  for (int j = 0; j < 16; ++j) {
    px[j]=xs[p0+j]; py[j]=ys[p0+j]; pz[j]=zs[p0+j]; dist[j]=1e10f;
  }
  const int wv = t >> 6;
  int cur = 0;
  for (int i = 0; i < NS; ++i) {
    float cx = xs[cur], cy = ys[cur], cz = zs[cur];
    if (t == 0) {
      size_t o = (size_t)(b*NS + i)*3;
      newxyz[o] = cx; newxyz[o+1] = cy; newxyz[o+2] = cz;
      size_t q = (size_t)b*3*NS + i;
      out0[q] = cx; out0[q + NS] = cy; out0[q + 2*NS] = cz;  // bit-exact copy
    }
    if (i == NS-1) break;
    float bv = -1.0f; int bi = p0;
    #pragma unroll
    for (int j = 0; j < 16; ++j) {
      float dx = __fsub_rn(px[j], cx);
      float dy = __fsub_rn(py[j], cy);
      float dz = __fsub_rn(pz[j], cz);
      float d  = __fadd_rn(__fadd_rn(__fmul_rn(dx,dx), __fmul_rn(dy,dy)), __fmul_rn(dz,dz));
      float nd = fminf(dist[j], d);
      dist[j] = nd;
      if (nd > bv) { bv = nd; bi = p0 + j; }   // strict > => first occurrence
    }
    // wave64 max via DPP chain (result converges to lane 63)
    float x = bv;
    x = fmax_dpp<0x111,0xF,0xF>(x);   // row_shr:1
    x = fmax_dpp<0x112,0xF,0xF>(x);   // row_shr:2
    x = fmax_dpp<0x114,0xF,0xF>(x);   // row_shr:4
    x = fmax_dpp<0x118,0xF,0xF>(x);   // row_shr:8
    x = fmax_dpp<0x142,0xA,0xF>(x);   // row_bcast:15 -> rows 1,3
    x = fmax_dpp<0x143,0xC,0xF>(x);   // row_bcast:31 -> rows 2,3
    float M = __int_as_float(__builtin_amdgcn_readlane(__float_as_int(x), 63));
    // first lane holding the max = smallest point index with the max value
    unsigned long long mk = __ballot(bv == M);
    int sl  = (int)__builtin_ctzll(mk);
    int wbi = __builtin_amdgcn_readlane(bi, sl);
    if ((t & 63) == 0) pair[i & 1][wv] = make_float2(M, __int_as_float(wbi));
    __syncthreads();
    const float4* pb = (const float4*)&pair[i & 1][0];
    float4 q01 = pb[0], q23 = pb[1];
    float bestv = q01.x; int besti = __float_as_int(q01.y);
    if (q01.z > bestv) { bestv = q01.z; besti = __float_as_int(q01.w); }
    if (q23.x > bestv) { bestv = q23.x; besti = __float_as_int(q23.y); }
    if (q23.z > bestv) { bestv = q23.z; besti = __float_as_int(q23.w); }
    cur = besti;   // uniform across block; no broadcast needed
  }
}

// ---------------- Ball query: one wave per query ----------------------------
__global__ __launch_bounds__(256) void k_ballq(const float* __restrict__ xyz,
                                               const float* __restrict__ newxyz,
                                               int* __restrict__ idx) {
  const int gw = (blockIdx.x * 256 + threadIdx.x) >> 6;   // global wave = query
  const int lane = threadIdx.x & 63;
  const int b = gw >> 10;
  const int s = gw & (NS-1);
  const float* xb = xyz + (size_t)b * 3 * NPTS;
  const size_t nq = (size_t)(b*NS + s)*3;
  const float nx = newxyz[nq], ny = newxyz[nq+1], nz = newxyz[nq+2];
  const float sn = __fadd_rn(__fadd_rn(__fmul_rn(nx,nx), __fmul_rn(ny,ny)), __fmul_rn(nz,nz));
  const float R2 = (float)(0.2*0.2);
  int* out = idx + (size_t)gw * NK;
  int cnt = 0, first = 0;
  for (int c0 = 0; c0 < NPTS; c0 += 64) {
    int n = c0 + lane;
    float x = xb[n], y = xb[NPTS+n], z = xb[2*NPTS+n];
    float sx = __fadd_rn(__fadd_rn(__fmul_rn(x,x), __fmul_rn(y,y)), __fmul_rn(z,z));
    float dt = __fadd_rn(__fadd_rn(__fmul_rn(nx,x), __fmul_rn(ny,y)), __fmul_rn(nz,z));
    float sqr = __fsub_rn(__fadd_rn(sn, sx), __fmul_rn(2.0f, dt));
    bool inr = (sqr <= R2);                 // kept iff NOT (sqr > r^2)
    unsigned long long m = __ballot(inr);
    if (m != 0ull) {
      if (cnt == 0) first = c0 + (int)__builtin_ctzll(m);
      int rank = __popcll(m & ((1ull << lane) - 1ull));
      int pos = cnt + rank;
      if (inr && pos < NK) out[pos] = n;
      cnt += __popcll(m);
      if (cnt >= NK) break;
    }
  }
  int tot = cnt < NK ? cnt : NK;
  if (lane >= tot && lane < NK) out[lane] = first;
}

// ---------------- Layer 1: gather + 6->64 conv -----------------------------
__global__ __launch_bounds__(256) void k_layer1(const float* __restrict__ xyz,
                                                const float* __restrict__ feat,
                                                const float* __restrict__ newxyz,
                                                const int* __restrict__ idx,
                                                const float* __restrict__ w0,
                                                const float* __restrict__ b0,
                                                bf16* __restrict__ x1) {
  __shared__ float w[64*6];
  __shared__ float bias[64];
  for (int i = threadIdx.x; i < 64*6; i += 256) w[i] = w0[i];
  if (threadIdx.x < 64) bias[threadIdx.x] = b0[threadIdx.x];
  __syncthreads();
  const int col = blockIdx.x * 256 + threadIdx.x;   // (b*NS+s)*NK + k
  const int bs = col >> 5;                          // b*NS + s
  const int b  = bs >> 10;
  const int n  = idx[col];
  const float* xb = xyz  + (size_t)b*3*NPTS;
  const float* fb = feat + (size_t)b*3*NPTS;
  float in[6];
  in[0] = __fsub_rn(xb[n],        newxyz[(size_t)bs*3]);
  in[1] = __fsub_rn(xb[NPTS+n],   newxyz[(size_t)bs*3+1]);
  in[2] = __fsub_rn(xb[2*NPTS+n], newxyz[(size_t)bs*3+2]);
  in[3] = fb[n];
  in[4] = fb[NPTS+n];
  in[5] = fb[2*NPTS+n];
  #pragma unroll
  for (int o = 0; o < 64; ++o) {
    float acc = bias[o];
    #pragma unroll
    for (int c = 0; c < 6; ++c) acc = fmaf(in[c], w[o*6+c], acc);
    x1[(size_t)o*NT_COLS + col] = __float2bfloat16(acc);
  }
}

// ---------------- Per-channel sum / sumsq (bf16 intermediates) --------------
__global__ __launch_bounds__(256) void k_stats(const bf16* __restrict__ x,
                                               float* __restrict__ accum, int C) {
  const int o = blockIdx.x >> 5;
  const int chunk = blockIdx.x & 31;
  const uint4* p = (const uint4*)(x + (size_t)o*NT_COLS + (size_t)chunk*16384);
  float s = 0.f, ss = 0.f;
  #pragma unroll
  for (int it = 0; it < 8; ++it) {
    uint4 u = p[threadIdx.x + it*256];
    uint32_t wr[4] = {u.x, u.y, u.z, u.w};
    #pragma unroll
    for (int q = 0; q < 4; ++q) {
      float a  = __uint_as_float(wr[q] << 16);
      float bq = __uint_as_float(wr[q] & 0xffff0000u);
      s += a;  ss = fmaf(a, a, ss);
      s += bq; ss = fmaf(bq, bq, ss);
    }
  }
  #pragma unroll
  for (int off = 32; off; off >>= 1) { s += __shfl_xor(s, off); ss += __shfl_xor(ss, off); }
  __shared__ float ls[4], lss[4];
  const int lane = threadIdx.x & 63, wv = threadIdx.x >> 6;
  if (lane == 0) { ls[wv] = s; lss[wv] = ss; }
  __syncthreads();
  if (threadIdx.x == 0) {
    atomicAdd(&accum[o],     (ls[0]+ls[1])+(ls[2]+ls[3]));
    atomicAdd(&accum[C + o], (lss[0]+lss[1])+(lss[2]+lss[3]));
  }
}

__global__ void k_finalize(const float* __restrict__ accum,
                           const float* __restrict__ g, const float* __restrict__ beta,
                           float* __restrict__ scsh, int C) {
  int o = blockIdx.x*256 + threadIdx.x;
  if (o < C) {
    const float n = (float)NT_COLS;
    float mu  = accum[o] / n;
    float var = accum[C+o] / n - mu*mu;
    if (var < 0.f) var = 0.f;
    float rs = rsqrtf(var + 1e-5f);
    float sc = g[o] * rs;
    scsh[o]   = sc;
    scsh[C+o] = beta[o] - mu * sc;
  }
}

// ---------------- Layers 2/3: BN+ReLU(in) then 64->CO GEMM -----------------
template<int CO>
__global__ __launch_bounds__(256) void k_layerN(const bf16* __restrict__ xin,
                                                const float* __restrict__ wN,
                                                const float* __restrict__ bN,
                                                const float* __restrict__ scsh,
                                                bf16* __restrict__ xout) {
  __shared__ float w[CO*64];
  __shared__ float bias[CO];
  __shared__ float sc[64], sh[64];
  for (int i = threadIdx.x; i < CO*64; i += 256) w[i] = wN[i];
  if (threadIdx.x < CO) bias[threadIdx.x] = bN[threadIdx.x];
  if (threadIdx.x < 64) { sc[threadIdx.x] = scsh[threadIdx.x]; sh[threadIdx.x] = scsh[64+threadIdx.x]; }
  __syncthreads();
  const int col = blockIdx.x * 256 + threadIdx.x;
  float y[64];
  #pragma unroll
  for (int c = 0; c < 64; ++c) {
    float v = __bfloat162float(xin[(size_t)c*NT_COLS + col]);
    v = fmaf(v, sc[c], sh[c]);
    y[c] = fmaxf(v, 0.f);
  }
  for (int o = 0; o < CO; ++o) {
    float acc = bias[o];
    #pragma unroll
    for (int c = 0; c < 64; ++c) acc = fmaf(w[o*64+c], y[c], acc);
    xout[(size_t)o*NT_COLS + col] = __float2bfloat16(acc);
  }
}

// ---------------- Max-pool over K with final BN+ReLU (fp32 out) -------------
__global__ __launch_bounds__(256) void k_maxpool(const bf16* __restrict__ x3,
                                                 const float* __restrict__ scsh,
                                                 float* __restrict__ out1) {
  const int t = blockIdx.x * 256 + threadIdx.x;  // (b*128+o)*NS + s
  const int s  = t & (NS-1);
  const int bo = t >> 10;
  const int o  = bo & 127;
  const int b  = bo >> 7;
  const float sc = scsh[o], sh = scsh[128+o];
  const uint4* p = (const uint4*)(x3 + (size_t)o*NT_COLS + (size_t)(b*NS + s)*NK);
  float m = 0.f;   // ReLU outputs are >= 0
  #pragma unroll
  for (int it = 0; it < 4; ++it) {
    uint4 u = p[it];
    uint32_t wr[4] = {u.x, u.y, u.z, u.w};
    #pragma unroll
    for (int q = 0; q < 4; ++q) {
      float a  = __uint_as_float(wr[q] << 16);
      float bq = __uint_as_float(wr[q] & 0xffff0000u);
      a  = fmaxf(fmaf(a,  sc, sh), 0.f);
      bq = fmaxf(fmaf(bq, sc, sh), 0.f);
      m = fmaxf(m, fmaxf(a, bq));
    }
  }
  out1[t] = m;
}

extern "C" void kernel_launch(void* const* d_in, const int* in_sizes, int n_in,
                              void* d_out, int out_size, void* d_ws, size_t ws_size,
                              hipStream_t stream) {
  const float* xyz  = (const float*)d_in[0];
  const float* feat = (const float*)d_in[1];
  const float* w0 = (const float*)d_in[2];
  const float* b0 = (const float*)d_in[3];
  const float* g0 = (const float*)d_in[4];
  const float* bt0= (const float*)d_in[5];
  const float* w1 = (const float*)d_in[6];
  const float* b1 = (const float*)d_in[7];
  const float* g1 = (const float*)d_in[8];
  const float* bt1= (const float*)d_in[9];
  const float* w2 = (const float*)d_in[10];
  const float* b2 = (const float*)d_in[11];
  const float* g2 = (const float*)d_in[12];
  const float* bt2= (const float*)d_in[13];

  float* out0 = (float*)d_out;                     // (B,3,NS) fp32
  float* out1 = out0 + (size_t)NB*3*NS;            // (B,128,NS) fp32

  // Workspace layout (total 203,628,544 B ~= 194 MB):
  //   accum@0, scsh@4096, newxyz@8192(fp32), bidx@204800,
  //   x2@2301952 (64MB), x1@69410816 (64MB), x3@69410816 (128MB, aliases dead x1)
  char* ws = (char*)d_ws;
  float* accum  = (float*)(ws + 0);
  float* scsh   = (float*)(ws + 4096);
  float* newxyz = (float*)(ws + 8192);
  int*   bidx   = (int*)  (ws + 204800);
  bf16*  x2     = (bf16*) (ws + 2301952);
  bf16*  x1     = (bf16*) (ws + 69410816);
  bf16*  x3     = (bf16*) (ws + 69410816);

  k_zero <<<1, 512, 0, stream>>>(accum);

  k_fps  <<<NB,   256, 0, stream>>>(xyz, newxyz, out0);
  k_ballq<<<16384/4, 256, 0, stream>>>(xyz, newxyz, bidx);
  k_layer1<<<NT_COLS/256, 256, 0, stream>>>(xyz, feat, newxyz, bidx, w0, b0, x1);

  k_stats   <<<64*32, 256, 0, stream>>>(x1, accum + 0, 64);
  k_finalize<<<1,     256, 0, stream>>>(accum + 0, g0, bt0, scsh + 0, 64);
  k_layerN<64><<<NT_COLS/256, 256, 0, stream>>>(x1, w1, b1, scsh + 0, x2);

  k_stats   <<<64*32, 256, 0, stream>>>(x2, accum + 128, 64);
  k_finalize<<<1,     256, 0, stream>>>(accum + 128, g1, bt1, scsh + 128, 64);
  k_layerN<128><<<NT_COLS/256, 256, 0, stream>>>(x2, w2, b2, scsh + 128, x3);

  k_stats   <<<128*32, 256, 0, stream>>>(x3, accum + 256, 128);
  k_finalize<<<1,      256, 0, stream>>>(accum + 256, g2, bt2, scsh + 256, 128);
  k_maxpool <<<(NB*128*NS)/256, 256, 0, stream>>>(x3, scsh + 256, out1);
}